// Round 5
// baseline (417.458 us; speedup 1.0000x reference)
//
#include <hip/hip_runtime.h>
#include <math.h>

namespace {

constexpr int B  = 8;
constexpr int S  = 4096;
constexpr int H  = 1024;
constexpr int NC = 16;
constexpr int NH = 4;
constexpr int HD = 256;
constexpr int LH = NH * NC;      // 64 score rows per batch, lh = h*NC + l
constexpr float RSQRT_HD = 0.0625f;   // 1/sqrt(256)
constexpr float REPS = 1e-6f;

typedef __attribute__((ext_vector_type(8))) short bhalf8;
typedef __attribute__((ext_vector_type(4))) short bhalf4;
typedef __attribute__((ext_vector_type(4))) float floatx4;

__device__ __forceinline__ unsigned short f2bf(float f) {
  unsigned u = __builtin_bit_cast(unsigned, f);
  u += 0x7fffu + ((u >> 16) & 1u);          // RNE
  return (unsigned short)(u >> 16);
}

__device__ __forceinline__ float bf2f(unsigned short u) {
  return __builtin_bit_cast(float, (unsigned)u << 16);
}

__device__ __forceinline__ bhalf8 pack8(float4 lo, float4 hi) {
  bhalf8 r;
  r[0] = (short)f2bf(lo.x); r[1] = (short)f2bf(lo.y);
  r[2] = (short)f2bf(lo.z); r[3] = (short)f2bf(lo.w);
  r[4] = (short)f2bf(hi.x); r[5] = (short)f2bf(hi.y);
  r[6] = (short)f2bf(hi.z); r[7] = (short)f2bf(hi.w);
  return r;
}

__device__ __forceinline__ float gelu_exact(float x) {
  return 0.5f * x * (1.0f + erff(x * 0.70710678118654752440f));
}

// ---------------- K_prep: W1 fp32 -> bf16 copy ----------------
__global__ __launch_bounds__(256) void k_prep(const float* __restrict__ W1,
                                              unsigned short* __restrict__ W1b) {
  int i = blockIdx.x * 256 + threadIdx.x;   // float4 granule; 65536 total
  float4 v = ((const float4*)W1)[i];
  bhalf4 o;
  o.x = (short)f2bf(v.x); o.y = (short)f2bf(v.y);
  o.z = (short)f2bf(v.z); o.w = (short)f2bf(v.w);
  ((bhalf4*)W1b)[i] = o;
}

// ---------------- K0: q[l][o] = cq[l] . Wq[o] + bq[o] ----------------
__global__ __launch_bounds__(256) void k_q(const float* __restrict__ cq,
                                           const float* __restrict__ Wq,
                                           const float* __restrict__ bq,
                                           float* __restrict__ q) {
  const int l = blockIdx.x;
  const int oc = blockIdx.y;                // 8 chunks of 128 o
  const int lane = threadIdx.x & 63;
  const int w = threadIdx.x >> 6;
  __shared__ __align__(16) float cqs[H];
  for (int i = threadIdx.x; i < H; i += 256) cqs[i] = cq[l * H + i];
  __syncthreads();
  float4 c4[4];
#pragma unroll
  for (int j = 0; j < 4; j++) c4[j] = ((const float4*)cqs)[lane * 4 + j];
  for (int oo = 0; oo < 32; oo++) {
    int o = oc * 128 + w * 32 + oo;
    const float4* wr = (const float4*)(Wq + (size_t)o * H) + lane * 4;
    float p = 0.f;
#pragma unroll
    for (int j = 0; j < 4; j++) {
      float4 wv = wr[j];
      p = fmaf(wv.x, c4[j].x, p); p = fmaf(wv.y, c4[j].y, p);
      p = fmaf(wv.z, c4[j].z, p); p = fmaf(wv.w, c4[j].w, p);
    }
#pragma unroll
    for (int off = 32; off; off >>= 1) p += __shfl_xor(p, off);
    if (lane == 0) q[l * H + o] = p + bq[o];
  }
}

// -------- K1: qkp[lh][c] = bf16( (1/sqrt(HD)) * q_head . Wk_head[:,c] )
__global__ __launch_bounds__(256) void k_qkproj(const float* __restrict__ q,
                                                const float* __restrict__ Wk,
                                                unsigned short* __restrict__ qkpb) {
  const int lh = blockIdx.x;            // lh = h*NC + l
  const int h = lh >> 4, l = lh & 15;
  const int c0 = blockIdx.y * 64;
  const int tid = threadIdx.x;
  const int lane = tid & 63;
  const int w = tid >> 6;
  __shared__ float qs[HD];
  __shared__ float part[4][64];
  if (tid < HD) qs[tid] = q[l * H + h * HD + tid];
  __syncthreads();
  float acc = 0.f, acc2 = 0.f;
#pragma unroll 8
  for (int dd = 0; dd < 64; dd += 2) {
    int d = w * 64 + dd;
    acc  = fmaf(qs[d],     Wk[(size_t)(h * HD + d) * H + c0 + lane],     acc);
    acc2 = fmaf(qs[d + 1], Wk[(size_t)(h * HD + d + 1) * H + c0 + lane], acc2);
  }
  part[w][lane] = acc + acc2;
  __syncthreads();
  if (tid < 64) {
    float s = part[0][tid] + part[1][tid] + part[2][tid] + part[3][tid];
    qkpb[lh * H + c0 + tid] = f2bf(s * RSQRT_HD);
  }
}

// ---------------- K2: fused scorer MLP + scores, barrier-free MFMA ----------
// Output D1[j=256][tok=64] (hid^T), D2[lh=64][tok=64]. A = W1b / qkpb rows
// (direct global, contiguous bf16); B = te^T (direct global fp32 -> bf16 in
// regs). NO LDS, NO barriers in K-loop -> loads pipeline across steps.
// Wave w owns j in [w*64,+64) (4 m-frags) and lh in [w*16,+16) (1 m-frag).
__global__ __launch_bounds__(256, 2) void k_fused(
    const float* __restrict__ te, const unsigned short* __restrict__ W1b,
    const float* __restrict__ b1, const float* __restrict__ W2,
    const float* __restrict__ b2, const unsigned short* __restrict__ qkpb,
    float* __restrict__ imp, float* __restrict__ sc) {
  // LDS: [0,17408) sl f32 [64][68]; [17408) b1s; [18432) w2s;
  //      [19456) red[64][5]; [20736) impl[64]
  __shared__ __align__(16) char smem[20992];
  const int tid  = threadIdx.x;
  const int lane = tid & 63;
  const int w    = tid >> 6;
  const int l15  = lane & 15;
  const int lk   = lane >> 4;
  const int tok0 = blockIdx.x * 64;
  const int bb = tok0 >> 12;
  const int s0 = tok0 & (S - 1);

  float* b1s  = (float*)(smem + 17408);
  float* w2s  = (float*)(smem + 18432);
  float* red  = (float*)(smem + 19456);
  float* impl = (float*)(smem + 20736);
  b1s[tid] = b1[tid];
  w2s[tid] = W2[tid];

  floatx4 acc1[4][4];
  floatx4 acc2[4];
#pragma unroll
  for (int mf = 0; mf < 4; mf++) {
#pragma unroll
    for (int nf = 0; nf < 4; nf++) acc1[mf][nf] = 0.f;
    acc2[mf] = 0.f;
  }

  const float* teb = te + (size_t)(tok0 + l15) * H + lk * 8;
  const unsigned short* w1b = W1b + (size_t)(w * 64 + l15) * H + lk * 8;
  const unsigned short* qkb = qkpb + (size_t)(w * 16 + l15) * H + lk * 8;

  for (int k = 0; k < H; k += 32) {
    bhalf8 bt[4];
#pragma unroll
    for (int nf = 0; nf < 4; nf++) {
      const float* tp = teb + (size_t)nf * 16 * H + k;
      float4 lo = *(const float4*)tp;
      float4 hi = *(const float4*)(tp + 4);
      bt[nf] = pack8(lo, hi);
    }
    bhalf8 a2 = *(const bhalf8*)(qkb + k);
#pragma unroll
    for (int mf = 0; mf < 4; mf++) {
      bhalf8 a1 = *(const bhalf8*)(w1b + (size_t)mf * 16 * H + k);
#pragma unroll
      for (int nf = 0; nf < 4; nf++)
        acc1[mf][nf] = __builtin_amdgcn_mfma_f32_16x16x32_bf16(
            a1, bt[nf], acc1[mf][nf], 0, 0, 0);
    }
#pragma unroll
    for (int nf = 0; nf < 4; nf++)
      acc2[nf] = __builtin_amdgcn_mfma_f32_16x16x32_bf16(
          a2, bt[nf], acc2[nf], 0, 0, 0);
  }
  __syncthreads();

  // ---- layer-2: p[nf] = sum_j gelu(hid[j][tok]) * W2[j], j in wave slice ----
  float p[4] = {0.f, 0.f, 0.f, 0.f};
#pragma unroll
  for (int mf = 0; mf < 4; mf++)
#pragma unroll
    for (int reg = 0; reg < 4; reg++) {
      int j = w * 64 + mf * 16 + lk * 4 + reg;
      float bj = b1s[j], wj = w2s[j];
#pragma unroll
      for (int nf = 0; nf < 4; nf++)
        p[nf] = fmaf(gelu_exact(acc1[mf][nf][reg] + bj), wj, p[nf]);
    }
#pragma unroll
  for (int nf = 0; nf < 4; nf++) {
    p[nf] += __shfl_xor(p[nf], 16);
    p[nf] += __shfl_xor(p[nf], 32);
  }
  if (lk == 0) {
#pragma unroll
    for (int nf = 0; nf < 4; nf++) red[(nf * 16 + l15) * 5 + w] = p[nf];
  }
  __syncthreads();
  if (tid < 64) {
    float s = red[tid * 5 + 0] + red[tid * 5 + 1] + red[tid * 5 + 2] +
              red[tid * 5 + 3] + b2[0];
    float im = 1.0f / (1.0f + expf(-s));
    impl[tid] = im;
    imp[tok0 + tid] = im;
  }
  __syncthreads();

  // ---- scale scores by imp, transpose via LDS, write sc[lh][s] ----
  float* sl = (float*)smem;   // [64 tok][68]
#pragma unroll
  for (int nf = 0; nf < 4; nf++)
#pragma unroll
    for (int reg = 0; reg < 4; reg++) {
      int token = nf * 16 + l15;
      int lh = w * 16 + lk * 4 + reg;
      sl[token * 68 + lh] = acc2[nf][reg] * impl[token];
    }
  __syncthreads();
#pragma unroll
  for (int i = 0; i < 16; i++) {
    int idx = tid + i * 256;
    int lh = idx >> 6, s = idx & 63;
    sc[(size_t)(bb * LH + lh) * S + s0 + s] = sl[s * 68 + lh];
  }
}

// ------- K4: softmax over S, one row per block; writes bf16 attn -------
__global__ __launch_bounds__(256) void k_softmax(const float* __restrict__ sc,
                                                 unsigned short* __restrict__ attn_bf) {
  const int tid = threadIdx.x;
  const size_t row = blockIdx.x;            // b*LH + lh
  const float4* r4 = (const float4*)(sc + row * S);
  __shared__ float redm[4], reds[4];
  float4 v[4];
  float m = -3.0e38f;
#pragma unroll
  for (int j = 0; j < 4; j++) {
    v[j] = r4[tid + j * 256];
    m = fmaxf(m, fmaxf(fmaxf(v[j].x, v[j].y), fmaxf(v[j].z, v[j].w)));
  }
#pragma unroll
  for (int off = 32; off; off >>= 1) m = fmaxf(m, __shfl_xor(m, off));
  if ((tid & 63) == 0) redm[tid >> 6] = m;
  __syncthreads();
  m = fmaxf(fmaxf(redm[0], redm[1]), fmaxf(redm[2], redm[3]));
  float ssum = 0.f;
#pragma unroll
  for (int j = 0; j < 4; j++) {
    v[j].x = expf(v[j].x - m); v[j].y = expf(v[j].y - m);
    v[j].z = expf(v[j].z - m); v[j].w = expf(v[j].w - m);
    ssum += (v[j].x + v[j].y) + (v[j].z + v[j].w);
  }
#pragma unroll
  for (int off = 32; off; off >>= 1) ssum += __shfl_xor(ssum, off);
  if ((tid & 63) == 0) reds[tid >> 6] = ssum;
  __syncthreads();
  ssum = (reds[0] + reds[1]) + (reds[2] + reds[3]);
  const float inv = 1.0f / ssum;
  bhalf4* out4 = (bhalf4*)(attn_bf + row * S);
#pragma unroll
  for (int j = 0; j < 4; j++) {
    bhalf4 o;
    o.x = (short)f2bf(v[j].x * inv); o.y = (short)f2bf(v[j].y * inv);
    o.z = (short)f2bf(v[j].z * inv); o.w = (short)f2bf(v[j].w * inv);
    out4[tid + j * 256] = o;
  }
}

// ---------------- K4b: attn_weights = mean over heads (bf16 in, f32 out) ----
__global__ __launch_bounds__(256) void k_attnmean(const unsigned short* __restrict__ attn_bf,
                                                  float* __restrict__ aw) {
  const int idx = blockIdx.x * 256 + threadIdx.x;   // 65536: 8 elems each
  const int s8 = idx & 511;
  const int l = (idx >> 9) & 15;
  const int b = idx >> 13;
  const unsigned short* base = attn_bf + ((size_t)b * LH + l) * S + s8 * 8;
  float acc[8] = {0.f, 0.f, 0.f, 0.f, 0.f, 0.f, 0.f, 0.f};
#pragma unroll
  for (int h = 0; h < 4; h++) {
    bhalf8 u = *(const bhalf8*)(base + (size_t)h * 16 * S);
#pragma unroll
    for (int e = 0; e < 8; e++) acc[e] += bf2f((unsigned short)u[e]);
  }
  float* o = aw + ((size_t)b * NC + l) * S + s8 * 8;
  float4 o0, o1;
  o0.x = acc[0] * 0.25f; o0.y = acc[1] * 0.25f;
  o0.z = acc[2] * 0.25f; o0.w = acc[3] * 0.25f;
  o1.x = acc[4] * 0.25f; o1.y = acc[5] * 0.25f;
  o1.z = acc[6] * 0.25f; o1.w = acc[7] * 0.25f;
  ((float4*)o)[0] = o0; ((float4*)o)[1] = o1;
}

// ------- K5: agg[b][lh][c] += sum_s attn[lh][s] te[s][c]  (bf16 MFMA) -------
// grid (8 c-chunks of 128, 8 s-splits of 512, 8 b). A-frags direct from
// global bf16 attn_bf (contiguous); only te^T staged in LDS.
__global__ __launch_bounds__(256) void k_agg(const unsigned short* __restrict__ attn_bf,
                                             const float* __restrict__ te,
                                             float* __restrict__ agg) {
  __shared__ __align__(16) char smem[16384];   // Bt [128 c][64 s] bf16 swz
  const int tid = threadIdx.x;
  const int lane = tid & 63;
  const int w = tid >> 6;
  const int l15 = lane & 15;
  const int lk = lane >> 4;
  const int c0 = blockIdx.x * 128;
  const int sbase = blockIdx.y * 512;
  const int b = blockIdx.z;

  floatx4 acc[4][2];
#pragma unroll
  for (int mf = 0; mf < 4; mf++) { acc[mf][0] = 0.f; acc[mf][1] = 0.f; }

  for (int ss = sbase; ss < sbase + 512; ss += 64) {
    __syncthreads();
    // ---- stage Bt: te[s][c] -> [c][s] bf16, s-pairs packed b32 ----
#pragma unroll
    for (int i = 0; i < 4; i++) {
      int idx = tid + i * 256;
      int c4 = idx & 31, sp = idx >> 5;   // c4: 32 float4 cols, sp: 32 s-pairs
      const float* tp = te + (size_t)(b * S + ss + sp * 2) * H + c0 + c4 * 4;
      float4 v0 = *(const float4*)tp;
      float4 v1 = *(const float4*)(tp + H);
      float a0[4] = {v0.x, v0.y, v0.z, v0.w};
      float a1[4] = {v1.x, v1.y, v1.z, v1.w};
      const int swz = (c4 & 7) << 4;
#pragma unroll
      for (int j = 0; j < 4; j++) {
        int c = c4 * 4 + j;
        unsigned pk = (unsigned)f2bf(a0[j]) | ((unsigned)f2bf(a1[j]) << 16);
        *(unsigned*)(smem + ((c * 128 + sp * 4) ^ swz)) = pk;
      }
    }
    __syncthreads();
#pragma unroll
    for (int ks = 0; ks < 2; ks++) {
      bhalf8 af[4];
#pragma unroll
      for (int mf = 0; mf < 4; mf++)
        af[mf] = *(const bhalf8*)(attn_bf +
            (size_t)(b * LH + mf * 16 + l15) * S + ss + ks * 32 + lk * 8);
#pragma unroll
      for (int nf = 0; nf < 2; nf++) {
        int c = w * 32 + nf * 16 + l15;
        bhalf8 bf = *(bhalf8*)(smem +
            ((c * 128 + (ks * 32 + lk * 8) * 2) ^ (((c >> 2) & 7) << 4)));
#pragma unroll
        for (int mf = 0; mf < 4; mf++)
          acc[mf][nf] = __builtin_amdgcn_mfma_f32_16x16x32_bf16(
              af[mf], bf, acc[mf][nf], 0, 0, 0);
      }
    }
  }
#pragma unroll
  for (int mf = 0; mf < 4; mf++)
#pragma unroll
    for (int nf = 0; nf < 2; nf++)
#pragma unroll
      for (int r = 0; r < 4; r++) {
        int lh = mf * 16 + lk * 4 + r;
        int c = c0 + w * 32 + nf * 16 + l15;
        atomicAdd(&agg[(size_t)(b * LH + lh) * H + c], acc[mf][nf][r]);
      }
}

// ---------------- K6a: ctx[bl][h*HD+d] += Wv_h slice . agg ----------------
__global__ __launch_bounds__(256) void k_ctx(const float* __restrict__ agg,
                                             const float* __restrict__ Wv,
                                             float* __restrict__ ctx) {
  __shared__ __align__(16) float ag_sl[32][68];
  __shared__ float wv_sl[32][65];
  const int tid = threadIdx.x;
  const int ji = tid & 31, ti = tid >> 5;
  const int h = blockIdx.x >> 1;        // 4 heads
  const int blh = blockIdx.x & 1;       // bl-half
  const int dc = blockIdx.y;            // 4 chunks of 64 d
  const int cs = blockIdx.z;            // 8 splits of 128 c
  float acc[8][2];
#pragma unroll
  for (int m = 0; m < 8; m++) { acc[m][0] = 0.f; acc[m][1] = 0.f; }

  for (int sl = 0; sl < 128; sl += 32) {
#pragma unroll
    for (int i = 0; i < 8; i++) {
      int idx = tid + i * 256;
      int bl_l = idx >> 5, c = idx & 31;
      int bl = blh * 64 + bl_l;
      int row = (bl >> 4) * LH + h * NC + (bl & 15);
      ag_sl[c][bl_l] = agg[(size_t)row * H + cs * 128 + sl + c];
    }
#pragma unroll
    for (int i = 0; i < 8; i++) {
      int idx = tid + i * 256;
      int d = idx >> 5, c = idx & 31;
      wv_sl[c][d] = Wv[(size_t)(h * HD + dc * 64 + d) * H + cs * 128 + sl + c];
    }
    __syncthreads();
#pragma unroll 2
    for (int c = 0; c < 32; c++) {
      float am[8];
#pragma unroll
      for (int g = 0; g < 2; g++) {
        float4 a = ((const float4*)&ag_sl[c][ti * 8])[g];
        am[g * 4 + 0] = a.x; am[g * 4 + 1] = a.y;
        am[g * 4 + 2] = a.z; am[g * 4 + 3] = a.w;
      }
      float w0 = wv_sl[c][ji], w1 = wv_sl[c][ji + 32];
#pragma unroll
      for (int m = 0; m < 8; m++) {
        acc[m][0] = fmaf(am[m], w0, acc[m][0]);
        acc[m][1] = fmaf(am[m], w1, acc[m][1]);
      }
    }
    __syncthreads();
  }
#pragma unroll
  for (int m = 0; m < 8; m++) {
    int bl = blh * 64 + ti * 8 + m;
    atomicAdd(&ctx[(size_t)bl * H + h * HD + dc * 64 + ji], acc[m][0]);
    atomicAdd(&ctx[(size_t)bl * H + h * HD + dc * 64 + ji + 32], acc[m][1]);
  }
}

// ---------------- K6b: outp[bl][o] += Wo[o] . (ctx[bl]+bv) ----------------
__global__ __launch_bounds__(256) void k_out(const float* __restrict__ ctx,
                                             const float* __restrict__ bv,
                                             const float* __restrict__ Wo,
                                             float* __restrict__ outp) {
  __shared__ __align__(16) float cx_sl[32][68];
  __shared__ float wo_sl[32][65];
  const int tid = threadIdx.x;
  const int ji = tid & 31, ti = tid >> 5;
  const int oc = blockIdx.x;            // 16 chunks of 64 o
  const int is = blockIdx.y;            // 8 splits of 128 i
  const int blh = blockIdx.z;           // bl-half
  float acc[8][2];
#pragma unroll
  for (int m = 0; m < 8; m++) { acc[m][0] = 0.f; acc[m][1] = 0.f; }

  for (int sl = 0; sl < 128; sl += 32) {
#pragma unroll
    for (int i = 0; i < 8; i++) {
      int idx = tid + i * 256;
      int bl_l = idx >> 5, ii = idx & 31;
      int gi = is * 128 + sl + ii;
      cx_sl[ii][bl_l] = ctx[(size_t)(blh * 64 + bl_l) * H + gi] + bv[gi];
    }
#pragma unroll
    for (int i = 0; i < 8; i++) {
      int idx = tid + i * 256;
      int o = idx >> 5, ii = idx & 31;
      wo_sl[ii][o] = Wo[(size_t)(oc * 64 + o) * H + is * 128 + sl + ii];
    }
    __syncthreads();
#pragma unroll 2
    for (int c = 0; c < 32; c++) {
      float am[8];
#pragma unroll
      for (int g = 0; g < 2; g++) {
        float4 a = ((const float4*)&cx_sl[c][ti * 8])[g];
        am[g * 4 + 0] = a.x; am[g * 4 + 1] = a.y;
        am[g * 4 + 2] = a.z; am[g * 4 + 3] = a.w;
      }
      float w0 = wo_sl[c][ji], w1 = wo_sl[c][ji + 32];
#pragma unroll
      for (int m = 0; m < 8; m++) {
        acc[m][0] = fmaf(am[m], w0, acc[m][0]);
        acc[m][1] = fmaf(am[m], w1, acc[m][1]);
      }
    }
    __syncthreads();
  }
#pragma unroll
  for (int m = 0; m < 8; m++) {
    int bl = blh * 64 + ti * 8 + m;
    atomicAdd(&outp[(size_t)bl * H + oc * 64 + ji], acc[m][0]);
    atomicAdd(&outp[(size_t)bl * H + oc * 64 + ji + 32], acc[m][1]);
  }
}

// ---------------- K6c: RMSNorm -> compressed ----------------
__global__ __launch_bounds__(256) void k_rms(const float* __restrict__ outp,
                                             const float* __restrict__ bo,
                                             const float* __restrict__ rw,
                                             float* __restrict__ comp) {
  const int tid = threadIdx.x;
  const int bl = blockIdx.x;
  __shared__ float red[4];
  float4 v = ((const float4*)(outp + (size_t)bl * H))[tid];
  float4 bb = ((const float4*)bo)[tid];
  v.x += bb.x; v.y += bb.y; v.z += bb.z; v.w += bb.w;
  float ss = v.x * v.x + v.y * v.y + v.z * v.z + v.w * v.w;
#pragma unroll
  for (int off = 32; off; off >>= 1) ss += __shfl_xor(ss, off);
  if ((tid & 63) == 0) red[tid >> 6] = ss;
  __syncthreads();
  ss = (red[0] + red[1]) + (red[2] + red[3]);
  const float rms = sqrtf(ss * (1.0f / H) + REPS);
  const float inv = 1.0f / rms;
  float4 w = ((const float4*)rw)[tid];
  float4 o;
  o.x = v.x * inv * w.x; o.y = v.y * inv * w.y;
  o.z = v.z * inv * w.z; o.w = v.w * inv * w.w;
  ((float4*)(comp + (size_t)bl * H))[tid] = o;
}

}  // namespace

extern "C" void kernel_launch(void* const* d_in, const int* in_sizes, int n_in,
                              void* d_out, int out_size, void* d_ws,
                              size_t ws_size, hipStream_t stream) {
  (void)in_sizes; (void)n_in; (void)out_size; (void)ws_size;
  const float* te   = (const float*)d_in[0];
  const float* W1   = (const float*)d_in[1];
  const float* b1   = (const float*)d_in[2];
  const float* W2   = (const float*)d_in[3];
  const float* b2   = (const float*)d_in[4];
  const float* cq   = (const float*)d_in[5];
  const float* Wq   = (const float*)d_in[6];
  const float* bq   = (const float*)d_in[7];
  const float* Wk   = (const float*)d_in[8];
  // d_in[9] = bk: constant over s -> softmax-invariant, dropped
  const float* Wv   = (const float*)d_in[10];
  const float* bv   = (const float*)d_in[11];
  const float* Wo   = (const float*)d_in[12];
  const float* bo   = (const float*)d_in[13];
  const float* rmsw = (const float*)d_in[14];

  float* out_comp = (float*)d_out;              // [B][NC][H]   = 131072
  float* out_imp  = out_comp + B * NC * H;      // [B][S]       =  32768
  float* out_attw = out_imp + B * S;            // [B][NC][S]   = 524288

  float* q    = (float*)d_ws;                   //  16384 f
  float* qkp_region = q + NC * H;               //  65536 f slot
  unsigned short* qkpb = (unsigned short*)qkp_region;
  float* sc   = qkp_region + LH * H;            // 2097152 f (raw scores)
  float* agg  = sc + (size_t)B * LH * S;        //  524288 f (atomic, zeroed)
  float* ctx  = agg + (size_t)B * LH * H;       //  131072 f (atomic, zeroed)
  float* outp = ctx + (size_t)B * NC * H;       //  131072 f (atomic, zeroed)
  unsigned short* W1b = (unsigned short*)(outp + B * NC * H);   // 262144 us
  unsigned short* attn_bf = W1b + 262144;       // [B][LH][S] bf16 = 2097152 us

  hipMemsetAsync(agg, 0, (size_t)(B * LH * H + 2 * B * NC * H) * sizeof(float),
                 stream);

  k_prep<<<256, 256, 0, stream>>>(W1, W1b);
  k_q<<<dim3(NC, 8), 256, 0, stream>>>(cq, Wq, bq, q);
  k_qkproj<<<dim3(LH, 16), 256, 0, stream>>>(q, Wk, qkpb);
  k_fused<<<B * S / 64, 256, 0, stream>>>(te, W1b, b1, W2, b2, qkpb,
                                          out_imp, sc);
  k_softmax<<<B * LH, 256, 0, stream>>>(sc, attn_bf);
  k_attnmean<<<256, 256, 0, stream>>>(attn_bf, out_attw);
  k_agg<<<dim3(8, 8, 8), 256, 0, stream>>>(attn_bf, te, agg);
  k_ctx<<<dim3(8, 4, 8), 256, 0, stream>>>(agg, Wv, ctx);
  k_out<<<dim3(16, 8, 2), 256, 0, stream>>>(ctx, bv, Wo, outp);
  k_rms<<<B * NC, 256, 0, stream>>>(outp, bo, rmsw, out_comp);
}